// Round 1
// baseline (145.052 us; speedup 1.0000x reference)
//
#include <hip/hip_runtime.h>

// Problem: LinearUpscaler — multi-hot embedding bag.
// out[b,s,e] = sum_{k: id!=0} W[e, id[b,s,k]] + bias[e]
// B=64, S=200, K=50, V=100000, E=128.  P = B*S = 12800 positions.

#define VOCAB 100000
#define EMBED 128
#define KITEMS 50
#define NPOS 12800

// ---------------- Kernel 1: transpose W [E,V] -> Wt [V,E] ----------------
// Tile: 32 v-values x 128 e-values (16 KB LDS). 3125 blocks (32*3125 = 100000).
__global__ __launch_bounds__(256) void wt_transpose_kernel(
    const float* __restrict__ W, float* __restrict__ Wt) {
    __shared__ float tile[32][129];   // +1 pad: load phase writes stride-129 -> conflict-free
    const int v0 = blockIdx.x * 32;
    const int t  = threadIdx.x;

    // Load phase: coalesced along v. thread -> (e, j): j = t&31, e walks t>>5 + 8*i
    {
        const int j = t & 31;
        const int v = v0 + j;
        int e = t >> 5;               // 0..7
        #pragma unroll
        for (int i = 0; i < 16; ++i, e += 8)
            tile[j][e] = W[(size_t)e * VOCAB + v];
    }
    __syncthreads();

    // Store phase: coalesced along e. thread -> (j, e): e = t&127, j walks t>>7 + 2*i
    {
        const int e = t & 127;
        int j = t >> 7;               // 0..1
        #pragma unroll
        for (int i = 0; i < 16; ++i, j += 2)
            Wt[(size_t)(v0 + j) * EMBED + e] = tile[j][e];
    }
}

// ---------------- Kernel 2: gather + sum + bias ----------------
// One wave (64 lanes) per position. Each lane owns 2 embed dims via float2.
// ids for the position are loaded once (lane k holds id k) and broadcast by __shfl,
// so the id!=0 branch is wave-uniform and the Wt row read is a single coalesced
// 512B transaction per wave.
__global__ __launch_bounds__(256) void gather_sum_kernel(
    const int* __restrict__ ids, const float* __restrict__ Wt,
    const float* __restrict__ bias, float* __restrict__ out) {
    const int lane = threadIdx.x & 63;
    const int pos  = blockIdx.x * 4 + (threadIdx.x >> 6);   // 4 waves/block

    const int* idp = ids + pos * KITEMS;
    int myid = (lane < KITEMS) ? idp[lane] : 0;

    const float2* __restrict__ Wt2 = (const float2*)Wt;
    float2 acc = ((const float2*)bias)[lane];

    #pragma unroll 10
    for (int k = 0; k < KITEMS; ++k) {
        int id = __shfl(myid, k);     // wave-uniform id
        if (id != 0) {
            float2 w = Wt2[(size_t)id * 64 + lane];
            acc.x += w.x;
            acc.y += w.y;
        }
    }
    ((float2*)out)[(size_t)pos * 64 + lane] = acc;
}

extern "C" void kernel_launch(void* const* d_in, const int* in_sizes, int n_in,
                              void* d_out, int out_size, void* d_ws, size_t ws_size,
                              hipStream_t stream) {
    const int*   ids  = (const int*)  d_in[0];   // [64,200,50] int
    const float* W    = (const float*)d_in[1];   // [128,100000] f32
    const float* bias = (const float*)d_in[2];   // [128] f32
    float*       out  = (float*)d_out;           // [64,200,128] f32
    float*       Wt   = (float*)d_ws;            // [100000,128] f32 = 51.2 MB scratch

    hipLaunchKernelGGL(wt_transpose_kernel, dim3(VOCAB / 32), dim3(256), 0, stream, W, Wt);
    hipLaunchKernelGGL(gather_sum_kernel, dim3(NPOS / 4), dim3(256), 0, stream, ids, Wt, bias, out);
}

// Round 3
// 137.921 us; speedup vs baseline: 1.0517x; 1.0517x over previous
//
#include <hip/hip_runtime.h>

// LinearUpscaler — multi-hot embedding bag.
// out[b,s,e] = sum_{k: id!=0} W[e, id[b,s,k]] + bias[e]
// B=64, S=200, K=50, V=100000, E=128.  P = 12800 positions.
//
// Plan: (1) transpose W [E,V] fp32 -> Wt [V,E] bf16 in d_ws (25.6 MB),
//       (2) wave-per-position gather of 256B rows, fp32 accumulate.

#define VOCAB 100000
#define EMBED 128
#define KITEMS 50
#define NPOS 12800
#define TV 64   // v-tile of the transpose

// f32 -> bf16 (round to nearest even), as raw ushort bits
__device__ __forceinline__ unsigned short f32_to_bf16_rne(float f) {
    union { float f; unsigned int u; } x;
    x.f = f;
    unsigned int r = x.u + 0x7FFFu + ((x.u >> 16) & 1u);
    return (unsigned short)(r >> 16);
}

// ---------------- Kernel 1: W [128,V] f32 -> Wt [V,128] bf16 ----------------
__global__ __launch_bounds__(256) void wt_transpose_bf16(
    const float* __restrict__ W, unsigned short* __restrict__ Wt) {
    __shared__ float tile[EMBED][TV + 1];   // pad to break power-of-2 strides
    const int v0 = blockIdx.x * TV;
    const int t  = threadIdx.x;

    // Load: float4 along v. 16 chunks of 4 v per e-row; 16 e-rows per pass, 8 passes.
    {
        const int vc  = (t & 15) * 4;
        const bool in = (v0 + vc + 4) <= VOCAB;   // VOCAB%4==0 -> chunk all-in or all-out
        int e = t >> 4;
        #pragma unroll
        for (int i = 0; i < 8; ++i, e += 16) {
            float4 w = in ? *(const float4*)&W[(size_t)e * VOCAB + v0 + vc]
                          : float4{0.f, 0.f, 0.f, 0.f};
            tile[e][vc + 0] = w.x; tile[e][vc + 1] = w.y;
            tile[e][vc + 2] = w.z; tile[e][vc + 3] = w.w;
        }
    }
    __syncthreads();

    // Store: each thread emits 4 e (ushort4 = 8B) for one v; half-wave writes a full
    // 256B Wt row. 8 v-rows per pass, 8 passes.
    {
        const int e0 = (t & 31) * 4;
        int v = t >> 5;
        #pragma unroll
        for (int i = 0; i < 8; ++i, v += 8) {
            if (v0 + v < VOCAB) {
                ushort4 o;
                o.x = f32_to_bf16_rne(tile[e0 + 0][v]);
                o.y = f32_to_bf16_rne(tile[e0 + 1][v]);
                o.z = f32_to_bf16_rne(tile[e0 + 2][v]);
                o.w = f32_to_bf16_rne(tile[e0 + 3][v]);
                *(ushort4*)&Wt[(size_t)(v0 + v) * EMBED + e0] = o;
            }
        }
    }
}

// ---------------- Kernel 2: gather + sum + bias ----------------
// One wave per position. Lane owns e = {2*lane, 2*lane+1} (one packed uint of the
// 256B bf16 row). ids broadcast via __shfl -> wave-uniform coalesced row reads.
__global__ __launch_bounds__(256) void gather_sum_bf16(
    const int* __restrict__ ids, const unsigned int* __restrict__ Wt32,
    const float* __restrict__ bias, float* __restrict__ out) {
    const int lane = threadIdx.x & 63;
    const int pos  = blockIdx.x * 4 + (threadIdx.x >> 6);   // 4 waves/block

    const int* idp = ids + pos * KITEMS;
    int myid = (lane < KITEMS) ? idp[lane] : 0;

    float2 acc = ((const float2*)bias)[lane];

    #pragma unroll 10
    for (int k = 0; k < KITEMS; ++k) {
        int id = __shfl(myid, k);                 // wave-uniform
        if (id != 0) {
            unsigned int w = Wt32[(size_t)id * 64 + lane];
            union { unsigned int u; float f; } lo, hi;
            lo.u = w << 16;            // bf16 e=2*lane   -> f32
            hi.u = w & 0xFFFF0000u;    // bf16 e=2*lane+1 -> f32
            acc.x += lo.f;
            acc.y += hi.f;
        }
    }
    ((float2*)out)[(size_t)pos * 64 + lane] = acc;
}

extern "C" void kernel_launch(void* const* d_in, const int* in_sizes, int n_in,
                              void* d_out, int out_size, void* d_ws, size_t ws_size,
                              hipStream_t stream) {
    const int*      ids  = (const int*)  d_in[0];   // [64,200,50]
    const float*    W    = (const float*)d_in[1];   // [128,100000] f32
    const float*    bias = (const float*)d_in[2];   // [128] f32
    float*          out  = (float*)d_out;           // [64,200,128] f32
    unsigned short* Wt   = (unsigned short*)d_ws;   // [100000,128] bf16 = 25.6 MB

    const int tblocks = (VOCAB + TV - 1) / TV;      // 1563
    hipLaunchKernelGGL(wt_transpose_bf16, dim3(tblocks), dim3(256), 0, stream, W, Wt);
    hipLaunchKernelGGL(gather_sum_bf16, dim3(NPOS / 4), dim3(256), 0, stream,
                       ids, (const unsigned int*)Wt, bias, out);
}